// Round 8
// baseline (340.422 us; speedup 1.0000x reference)
//
#include <hip/hip_runtime.h>
#include <stdint.h>

#define B_   2
#define S_   2048
#define DM   1024
#define FIN  11264
#define DOUT 5120
#define NSH  8
#define DH   128
#define ROWS (B_*S_)

typedef __attribute__((ext_vector_type(8))) __bf16 bf16x8;
typedef __attribute__((ext_vector_type(4))) __bf16 bf16x4;
typedef __attribute__((ext_vector_type(4))) float  f32x4;

union U2 { unsigned int u; __bf16 h[2]; };

__device__ __forceinline__ void gload16(const void* g, void* l) {
    __builtin_amdgcn_global_load_lds((const __attribute__((address_space(1))) void*)g,
                                     (__attribute__((address_space(3))) void*)l, 16, 0, 0);
}

// ---------------- LayerNorm: x f32 (ROWS x DM) -> h bf16 ----------------
__global__ __launch_bounds__(256) void ln_kernel(const float* __restrict__ x,
                                                 const float* __restrict__ sc,
                                                 const float* __restrict__ of,
                                                 __bf16* __restrict__ h) {
    int row = blockIdx.x, t = threadIdx.x;
    const float4 v = *(const float4*)&x[(size_t)row*DM + t*4];
    float s  = v.x + v.y + v.z + v.w;
    float ss = v.x*v.x + v.y*v.y + v.z*v.z + v.w*v.w;
#pragma unroll
    for (int off = 32; off >= 1; off >>= 1) {
        s  += __shfl_xor(s, off);
        ss += __shfl_xor(ss, off);
    }
    __shared__ float rs_[4], rss_[4];
    int wid = t >> 6, lane = t & 63;
    if (lane == 0) { rs_[wid] = s; rss_[wid] = ss; }
    __syncthreads();
    s  = rs_[0] + rs_[1] + rs_[2] + rs_[3];
    ss = rss_[0] + rss_[1] + rss_[2] + rss_[3];
    float mu  = s * (1.f/DM);
    float var = ss * (1.f/DM) - mu*mu;
    float r   = rsqrtf(var + 1e-5f);
    float4 scv = *(const float4*)&sc[t*4];
    float4 ofv = *(const float4*)&of[t*4];
    bf16x4 o;
    o[0] = (__bf16)((v.x-mu)*r*scv.x + ofv.x);
    o[1] = (__bf16)((v.y-mu)*r*scv.y + ofv.y);
    o[2] = (__bf16)((v.z-mu)*r*scv.z + ofv.z);
    o[3] = (__bf16)((v.w-mu)*r*scv.w + ofv.w);
    *(bf16x4*)&h[(size_t)row*DM + t*4] = o;
}

// ------------- transpose+cast: in R x C f32 -> out C x R bf16 -----------
__global__ __launch_bounds__(256) void transpose_kernel(const float* __restrict__ in,
                                                        __bf16* __restrict__ out,
                                                        int R, int C) {
    __shared__ __bf16 tile[64][72];
    int c0 = blockIdx.x * 64, r0 = blockIdx.y * 64;
    int t = threadIdx.x;
#pragma unroll
    for (int it = 0; it < 4; ++it) {
        int flat = it*1024 + t*4;
        int rl = flat >> 6, cl = flat & 63;
        float4 v = *(const float4*)&in[(size_t)(r0+rl)*C + c0 + cl];
        tile[rl][cl+0] = (__bf16)v.x;
        tile[rl][cl+1] = (__bf16)v.y;
        tile[rl][cl+2] = (__bf16)v.z;
        tile[rl][cl+3] = (__bf16)v.w;
    }
    __syncthreads();
#pragma unroll
    for (int it = 0; it < 4; ++it) {
        int flat = it*1024 + t*4;
        int cl = flat >> 6, rl = flat & 63;
        bf16x4 o;
#pragma unroll
        for (int j = 0; j < 4; ++j) o[j] = tile[rl+j][cl];
        *(bf16x4*)&out[(size_t)(c0+cl)*R + r0 + rl] = o;
    }
}

// -------- bf16 transpose: in [Z][R=S_][C=DH] -> out [Z][C][R], swizzled LDS --------
__global__ __launch_bounds__(256) void vtrans_kernel(const __bf16* __restrict__ in,
                                                     __bf16* __restrict__ out) {
    __shared__ __bf16 tile[64*72];
    int d0 = blockIdx.x*64, s0 = blockIdx.y*64;
    size_t base = (size_t)blockIdx.z * (size_t)S_ * DH;
    int t = threadIdx.x;
#pragma unroll
    for (int it = 0; it < 2; ++it) {
        int idx = it*2048 + t*8;
        int sl = idx >> 6, dl = idx & 63;       // dl multiple of 8
        bf16x8 v = *(const bf16x8*)&in[base + (size_t)(s0+sl)*DH + d0+dl];
        int ch = ((dl>>3) ^ (sl&7) ^ ((sl>>3)&7)) & 7;
        *(bf16x8*)&tile[sl*72 + ch*8] = v;
    }
    __syncthreads();
#pragma unroll
    for (int it = 0; it < 2; ++it) {
        int idx = it*2048 + t*8;
        int dl = idx >> 6, sl = idx & 63;       // sl multiple of 8
        bf16x8 o;
#pragma unroll
        for (int j = 0; j < 8; ++j) {
            int r = sl + j;
            int ch = ((dl>>3) ^ (r&7) ^ ((r>>3)&7)) & 7;
            o[j] = tile[r*72 + ch*8 + (dl&7)];
        }
        *(bf16x8*)&out[base + (size_t)(d0+dl)*S_ + s0 + sl] = o;
    }
}

// ======== 128x128 m97-style GEMM, BK=64, single-buffered, 4 blocks/CU ========
// 256 threads, 4 waves (2Mx2N), LDS 32KB, rows 128B XOR-swizzled (byte^=(row&7)<<4)
// via pre-swizzled global source. Per K-step: 8 gload -> sync -> frags+MFMA -> sync.
// Cross-block overlap (3-4 blocks/CU) hides the vmcnt(0) drain (m97/m114 pattern).
__global__ __launch_bounds__(256, 4) void gemm128_kernel(const __bf16* __restrict__ A,
                                                         const __bf16* __restrict__ BT,
                                                         const float* __restrict__ bias,
                                                         __bf16* __restrict__ Cb,
                                                         float* __restrict__ Cf,
                                                         int M, int N, int K, int klen) {
    __shared__ __align__(16) char lds[32768];           // As 16K | Bs 16K
    int t = threadIdx.x, wid = t >> 6, lane = t & 63;
    int wm = (wid >> 1) * 64, wn = (wid & 1) * 64;
    int fr = lane & 15, fq = lane >> 4;
    int kbeg = blockIdx.z * klen;
    // bijective XCD swizzle (nwg_xy multiple of 8)
    int nbx = gridDim.x;
    int bid = blockIdx.y * nbx + blockIdx.x;
    int cpx = (nbx * gridDim.y) >> 3;
    int swz = (bid & 7) * cpx + (bid >> 3);
    int bx = swz % nbx, by = swz / nbx;
    int m0 = by * 128, n0 = bx * 128;

    // staging sources (pre-swizzled global addresses); chunk j = LDS bytes [j*4096, j*4096+4096)
    const __bf16* srcA[4];
    const __bf16* srcB[4];
#pragma unroll
    for (int j = 0; j < 4; ++j) {
        int F = (j*256 + t) * 16;
        int row = F >> 7;
        int c = (F & 127) ^ ((row & 7) << 4);
        srcA[j] = A  + (size_t)(m0 + row) * K + kbeg + (c >> 1);
        srcB[j] = BT + (size_t)(n0 + row) * K + kbeg + (c >> 1);
    }
    // fragment LDS byte offsets
    int rowA[4], rowB[4];
#pragma unroll
    for (int i = 0; i < 4; ++i) {
        rowA[i] = (wm + i*16 + fr) * 128;
        rowB[i] = 16384 + (wn + i*16 + fr) * 128;
    }
    int swzb = (fr & 7) << 4;
    int cb0 = (fq*16) ^ swzb;
    int cb1 = (64 + fq*16) ^ swzb;

    f32x4 acc[4][4] = {};
    for (int k0 = 0; k0 < klen; k0 += 64) {
#pragma unroll
        for (int j = 0; j < 4; ++j)
            gload16(srcA[j] + k0, lds + j*4096 + wid*1024);
#pragma unroll
        for (int j = 0; j < 4; ++j)
            gload16(srcB[j] + k0, lds + 16384 + j*4096 + wid*1024);
        __syncthreads();
        bf16x8 a[4], b[4];
        // k-half 0
#pragma unroll
        for (int i = 0; i < 4; ++i) a[i] = *(const bf16x8*)(lds + rowA[i] + cb0);
#pragma unroll
        for (int n = 0; n < 4; ++n) b[n] = *(const bf16x8*)(lds + rowB[n] + cb0);
#pragma unroll
        for (int i = 0; i < 4; ++i)
#pragma unroll
            for (int n = 0; n < 4; ++n)
                acc[i][n] = __builtin_amdgcn_mfma_f32_16x16x32_bf16(a[i], b[n], acc[i][n], 0, 0, 0);
        // k-half 1
#pragma unroll
        for (int i = 0; i < 4; ++i) a[i] = *(const bf16x8*)(lds + rowA[i] + cb1);
#pragma unroll
        for (int n = 0; n < 4; ++n) b[n] = *(const bf16x8*)(lds + rowB[n] + cb1);
#pragma unroll
        for (int i = 0; i < 4; ++i)
#pragma unroll
            for (int n = 0; n < 4; ++n)
                acc[i][n] = __builtin_amdgcn_mfma_f32_16x16x32_bf16(a[i], b[n], acc[i][n], 0, 0, 0);
        __syncthreads();
    }
    // epilogue
    int rq = fq * 4;
    if (Cb) {
#pragma unroll
        for (int i = 0; i < 4; ++i)
#pragma unroll
            for (int n = 0; n < 4; ++n) {
                int col = n0 + wn + n*16 + fr;
                float bv = bias[col];
#pragma unroll
                for (int r = 0; r < 4; ++r) {
                    int row = m0 + wm + i*16 + rq + r;
                    Cb[(size_t)row*N + col] = (__bf16)(acc[i][n][r] + bv);
                }
            }
    } else {
        float* Cz = Cf + (size_t)blockIdx.z * M * N;
#pragma unroll
        for (int i = 0; i < 4; ++i)
#pragma unroll
            for (int n = 0; n < 4; ++n) {
                int col = n0 + wn + n*16 + fr;
#pragma unroll
                for (int r = 0; r < 4; ++r) {
                    int row = m0 + wm + i*16 + rq + r;
                    Cz[(size_t)row*N + col] = acc[i][n][r];
                }
            }
    }
}

// ---------------- out = p0+p1+p2+p3 + bias (f32, vectorized) ----------------
__global__ __launch_bounds__(256) void addbias_kernel(const float* __restrict__ pk,
                                                      const float* __restrict__ bias,
                                                      float* __restrict__ out) {
    int idx = blockIdx.x * 256 + threadIdx.x;     // over ROWS*DM/4
    const size_t stride = (size_t)ROWS * DM / 4;
    float4 a0 = ((const float4*)pk)[idx];
    float4 a1 = ((const float4*)pk)[idx + stride];
    float4 a2 = ((const float4*)pk)[idx + 2*stride];
    float4 a3 = ((const float4*)pk)[idx + 3*stride];
    float4 bb = ((const float4*)bias)[idx & 255];
    float4 o;
    o.x = a0.x + a1.x + a2.x + a3.x + bb.x;
    o.y = a0.y + a1.y + a2.y + a3.y + bb.y;
    o.z = a0.z + a1.z + a2.z + a3.z + bb.z;
    o.w = a0.w + a1.w + a2.w + a3.w + bb.w;
    ((float4*)out)[idx] = o;
}

// ------- split proj -> q (rotary, *0.125), k (rotary), v ; (b,h,s,d) -------
__global__ __launch_bounds__(256) void qkv_rope_kernel(const __bf16* __restrict__ proj,
                                                       __bf16* __restrict__ qh,
                                                       __bf16* __restrict__ kh,
                                                       __bf16* __restrict__ vh) {
    int idx = blockIdx.x * 256 + threadIdx.x;   // ROWS*8*64
    int i   = idx & 63;          // pair index -> dims (2i, 2i+1)
    int p   = (idx >> 6) & 7;
    int row = idx >> 9;
    int s   = row & (S_ - 1);
    int b   = row >> 11;
    const __bf16* base = proj + (size_t)row*FIN + p*1408;
    int d0 = i*2;
    U2 uq, uv, uk;
    uq.u = *(const unsigned int*)&base[d0];
    uv.u = *(const unsigned int*)&base[128+d0];   // reference order: q, v, k
    uk.u = *(const unsigned int*)&base[256+d0];
    float q0 = uq.h[0], q1 = uq.h[1];
    float v0 = uv.h[0], v1 = uv.h[1];
    float k0 = uk.h[0], k1 = uk.h[1];
    if (d0 < 64) {
        float inv = exp2f(-(float)i * 0.4152410118609203f);   // 10000^(-i/32)
        float ang = (float)s * inv;
        float cn = __cosf(ang), sn = __sinf(ang);
        float a;
        a = q0*cn - q1*sn; q1 = q1*cn + q0*sn; q0 = a;
        a = k0*cn - k1*sn; k1 = k1*cn + k0*sn; k0 = a;
    }
    size_t o = ((size_t)((b*NSH + p)*S_ + s))*DH + d0;
    U2 oq, ok, ov;
    oq.h[0] = (__bf16)(q0*0.125f); oq.h[1] = (__bf16)(q1*0.125f);
    ok.h[0] = (__bf16)k0;          ok.h[1] = (__bf16)k1;
    ov.h[0] = (__bf16)v0;          ov.h[1] = (__bf16)v1;
    *(unsigned int*)&qh[o] = oq.u;
    *(unsigned int*)&kh[o] = ok.u;
    *(unsigned int*)&vh[o] = ov.u;
}

// ----------------- GLU: ff_out * gelu_tanh(ff_gate) -> combined -----------------
__global__ __launch_bounds__(256) void glu_kernel(const __bf16* __restrict__ proj,
                                                  __bf16* __restrict__ ag) {
    int idx = blockIdx.x * 256 + threadIdx.x;   // ROWS*8*256, 2 elems each
    int j2  = (idx & 255) * 2;
    int p   = (idx >> 8) & 7;
    int row = idx >> 11;
    const __bf16* bp = proj + (size_t)row*FIN + p*1408;
    U2 xo, xg, o;
    xo.u = *(const unsigned int*)&bp[384 + j2];
    xg.u = *(const unsigned int*)&bp[896 + j2];
#pragma unroll
    for (int j = 0; j < 2; ++j) {
        float g = xg.h[j];
        float e2 = __expf(1.5957691216057308f*(g + 0.044715f*g*g*g));  // e^{2u}
        float gl = g * (1.f - 1.f/(e2 + 1.f));                          // g*tanh-gelu
        o.h[j] = (__bf16)((float)xo.h[j] * gl);
    }
    *(unsigned int*)&ag[(size_t)row*DOUT + p*640 + 128 + j2] = o.u;
}

// ---------------------- flash attention, causal + bias ----------------------
__device__ __forceinline__ void stage_kv(const __bf16* Kb, const __bf16* Vg,
                                         char* KsB, char* VsB,
                                         int kvbase, int t, int wid) {
#pragma unroll
    for (int j = 0; j < 4; ++j) {
        int F = (j*256 + t)*16;
        int r = F >> 8, c = F & 255;
        gload16(Kb + (size_t)(kvbase + r)*DH + ((c ^ ((r & 7) << 4)) >> 1),
                KsB + j*4096 + (wid << 10));
    }
#pragma unroll
    for (int j = 0; j < 4; ++j) {
        int F = (j*256 + t)*16;
        int r = F >> 7, c = F & 127;
        gload16(Vg + (size_t)r*S_ + kvbase + ((c ^ ((r & 7) << 4)) >> 1),
                VsB + j*4096 + (wid << 10));
    }
}

__global__ __launch_bounds__(256, 2) void attn_kernel(const __bf16* __restrict__ qh,
                                                      const __bf16* __restrict__ kh,
                                                      const __bf16* __restrict__ vt,
                                                      const float* __restrict__ ab,
                                                      __bf16* __restrict__ ag) {
    __shared__ __bf16 Ks[2*8192];     // 2 x [64][128]
    __shared__ __bf16 Vs[2*8192];     // 2 x [128][64]
    __shared__ __bf16 Ps[4][16*72];
    int bh = blockIdx.y;
    int b = bh >> 3, hh = bh & 7;
    int xr = blockIdx.x;
    int qb = (xr & 1) ? (31 - (xr >> 1)) : (xr >> 1);   // causal load balance
    int q0 = qb * 64;
    int t = threadIdx.x, wid = t >> 6, lane = t & 63;
    int fr = lane & 15, fkb = (lane >> 4) * 16;   // byte offset of k-start
    const __bf16* Qb = qh + (size_t)bh * S_ * DH;
    const __bf16* Kb = kh + (size_t)bh * S_ * DH;
    const __bf16* Vg = vt + (size_t)bh * DH * S_;
    bf16x8 qf[4];
#pragma unroll
    for (int kk = 0; kk < 4; ++kk)
        qf[kk] = *(const bf16x8*)&Qb[(size_t)(q0 + wid*16 + fr)*DH + kk*32 + (lane>>4)*8];
    float m[4] = {-3e38f, -3e38f, -3e38f, -3e38f};
    float l[4] = {0.f, 0.f, 0.f, 0.f};
    f32x4 o[8] = {};
    int rowb = q0 + wid*16 + (lane >> 4)*4;
    int nit = qb + 1;
    stage_kv(Kb, Vg, (char*)Ks, (char*)Vs, 0, t, wid);
    for (int it = 0; it < nit; ++it) {
        int kv0 = it * 64, cur = it & 1;
        float abv[4][4];
#pragma unroll
        for (int n = 0; n < 4; ++n)
#pragma unroll
            for (int r = 0; r < 4; ++r)
                abv[n][r] = ab[(size_t)(rowb + r)*S_ + kv0 + n*16 + fr];
        if (it + 1 < nit) {
            stage_kv(Kb, Vg, (char*)Ks + (cur^1)*16384, (char*)Vs + (cur^1)*16384,
                     kv0 + 64, t, wid);
            asm volatile("s_waitcnt vmcnt(8)" ::: "memory");
        } else {
            asm volatile("s_waitcnt vmcnt(0)" ::: "memory");
        }
        __builtin_amdgcn_s_barrier();
        // ---- QK^T ----
        const char* KsC = (const char*)Ks + cur*16384;
        float pv[4][4];
        __builtin_amdgcn_s_setprio(1);
#pragma unroll
        for (int n = 0; n < 4; ++n) {
            f32x4 sacc = {};
#pragma unroll
            for (int kk = 0; kk < 4; ++kk) {
                int row = n*16 + fr;
                int c2 = (kk*64 + fkb) ^ ((fr & 7) << 4);
                bf16x8 kf = *(const bf16x8*)(KsC + row*256 + c2);
                sacc = __builtin_amdgcn_mfma_f32_16x16x32_bf16(qf[kk], kf, sacc, 0, 0, 0);
            }
#pragma unroll
            for (int r = 0; r < 4; ++r) pv[n][r] = sacc[r];
        }
        __builtin_amdgcn_s_setprio(0);
        // ---- bias + causal + online softmax ----
#pragma unroll
        for (int n = 0; n < 4; ++n) {
            int col = kv0 + n*16 + fr;
#pragma unroll
            for (int r = 0; r < 4; ++r)
                pv[n][r] += abv[n][r] + (col <= rowb + r ? 0.f : -1e10f);
        }
        float alpha[4];
#pragma unroll
        for (int r = 0; r < 4; ++r) {
            float mx = fmaxf(fmaxf(pv[0][r], pv[1][r]), fmaxf(pv[2][r], pv[3][r]));
#pragma unroll
            for (int off = 8; off >= 1; off >>= 1) mx = fmaxf(mx, __shfl_xor(mx, off));
            float mn = fmaxf(m[r], mx);
            alpha[r] = __expf(m[r] - mn);
            m[r] = mn;
            float sum = 0.f;
#pragma unroll
            for (int n = 0; n < 4; ++n) { pv[n][r] = __expf(pv[n][r] - mn); sum += pv[n][r]; }
#pragma unroll
            for (int off = 8; off >= 1; off >>= 1) sum += __shfl_xor(sum, off);
            l[r] = l[r]*alpha[r] + sum;
        }
#pragma unroll
        for (int nf = 0; nf < 8; ++nf)
#pragma unroll
            for (int r = 0; r < 4; ++r) o[nf][r] *= alpha[r];
        // ---- P -> LDS (per-wave) ----
#pragma unroll
        for (int n = 0; n < 4; ++n)
#pragma unroll
            for (int r = 0; r < 4; ++r)
                Ps[wid][((lane >> 4)*4 + r)*72 + n*16 + fr] = (__bf16)pv[n][r];
        asm volatile("s_waitcnt lgkmcnt(0)" ::: "memory");
        __builtin_amdgcn_sched_barrier(0);
        bf16x8 pf[2];
#pragma unroll
        for (int kk = 0; kk < 2; ++kk)
            pf[kk] = *(const bf16x8*)&Ps[wid][fr*72 + kk*32 + (lane>>4)*8];
        // ---- PV ----
        const char* VsC = (const char*)Vs + cur*16384;
        __builtin_amdgcn_s_setprio(1);
#pragma unroll
        for (int nf = 0; nf < 8; ++nf) {
#pragma unroll
            for (int kk = 0; kk < 2; ++kk) {
                int row = nf*16 + fr;
                int c2 = (kk*64 + fkb) ^ ((fr & 7) << 4);
                bf16x8 vf = *(const bf16x8*)(VsC + row*128 + c2);
                o[nf] = __builtin_amdgcn_mfma_f32_16x16x32_bf16(pf[kk], vf, o[nf], 0, 0, 0);
            }
        }
        __builtin_amdgcn_s_setprio(0);
        asm volatile("s_waitcnt lgkmcnt(0)" ::: "memory");
        __builtin_amdgcn_sched_barrier(0);
        __builtin_amdgcn_s_barrier();
    }
    int rq = (lane >> 4) * 4;
#pragma unroll
    for (int r = 0; r < 4; ++r) {
        float inv = 1.f / l[r];
#pragma unroll
        for (int nf = 0; nf < 8; ++nf) {
            int qr = q0 + wid*16 + rq + r;
            int d = nf*16 + fr;
            ag[((size_t)(b*S_ + qr))*DOUT + hh*640 + d] = (__bf16)(o[nf][r] * inv);
        }
    }
}

extern "C" void kernel_launch(void* const* d_in, const int* in_sizes, int n_in,
                              void* d_out, int out_size, void* d_ws, size_t ws_size,
                              hipStream_t stream) {
    const float* x     = (const float*)d_in[0];
    const float* ab    = (const float*)d_in[1];
    const float* lns   = (const float*)d_in[2];
    const float* lno   = (const float*)d_in[3];
    const float* w_in  = (const float*)d_in[4];
    const float* b_in  = (const float*)d_in[5];
    const float* w_out = (const float*)d_in[6];
    const float* b_out = (const float*)d_in[7];
    float* out = (float*)d_out;
    char* ws = (char*)d_ws;

    __bf16* w_in_t  = (__bf16*)(ws);                 // 11264x1024  (23,068,672 B)
    __bf16* w_out_t = (__bf16*)(ws +  23068672);     // 1024x5120   (10,485,760 B)
    __bf16* hbuf    = (__bf16*)(ws +  33554432);     // 4096x1024   ( 8,388,608 B)
    __bf16* proj    = (__bf16*)(ws +  41943040);     // 4096x11264  (92,274,688 B)
    __bf16* vtb     = (__bf16*)(ws +  41943040);     // reuses proj after glu/rope
    float*  pk      = (float*)(ws +  52428800);      // 4 x 4096x1024 f32 partials (67,108,864 B)
    __bf16* qh      = (__bf16*)(ws + 134217728);     // 2x8x2048x128
    __bf16* kh      = (__bf16*)(ws + 142606336);
    __bf16* vh      = (__bf16*)(ws + 150994944);
    __bf16* agb     = (__bf16*)(ws + 159383552);     // 4096x5120   (41,943,040 B)

    transpose_kernel<<<dim3(FIN/64, DM/64), 256, 0, stream>>>(w_in, w_in_t, DM, FIN);
    transpose_kernel<<<dim3(DM/64, DOUT/64), 256, 0, stream>>>(w_out, w_out_t, DOUT, DM);
    ln_kernel<<<ROWS, 256, 0, stream>>>(x, lns, lno, hbuf);
    gemm128_kernel<<<dim3(FIN/128, ROWS/128, 1), 256, 0, stream>>>(hbuf, w_in_t, b_in,
                                                                   proj, nullptr,
                                                                   ROWS, FIN, DM, DM);
    qkv_rope_kernel<<<(ROWS*8*64)/256, 256, 0, stream>>>(proj, qh, kh, vh);
    glu_kernel<<<(ROWS*8*256)/256, 256, 0, stream>>>(proj, agb);
    vtrans_kernel<<<dim3(DH/64, S_/64, B_*NSH), 256, 0, stream>>>(vh, vtb);
    attn_kernel<<<dim3(S_/64, B_*NSH), 256, 0, stream>>>(qh, kh, vtb, ab, agb);
    gemm128_kernel<<<dim3(DM/128, ROWS/128, 4), 256, 0, stream>>>(agb, w_out_t, nullptr,
                                                                  nullptr, pk,
                                                                  ROWS, DM, DOUT, DOUT/4);
    addbias_kernel<<<ROWS*DM/1024, 256, 0, stream>>>(pk, b_out, out);
}

// Round 9
// 292.601 us; speedup vs baseline: 1.1634x; 1.1634x over previous
//
#include <hip/hip_runtime.h>
#include <stdint.h>

#define B_   2
#define S_   2048
#define DM   1024
#define FIN  11264
#define DOUT 5120
#define NSH  8
#define DH   128
#define ROWS (B_*S_)

typedef __attribute__((ext_vector_type(8))) __bf16 bf16x8;
typedef __attribute__((ext_vector_type(4))) __bf16 bf16x4;
typedef __attribute__((ext_vector_type(4))) float  f32x4;

union U2 { unsigned int u; __bf16 h[2]; };

__device__ __forceinline__ void gload16(const void* g, void* l) {
    __builtin_amdgcn_global_load_lds((const __attribute__((address_space(1))) void*)g,
                                     (__attribute__((address_space(3))) void*)l, 16, 0, 0);
}

// column permutation: newcol -> original w_in column
// [0,3072): p*384 + {q,v,k}  ;  [3072,11264): shard p, 16-col out/gate interleave
__device__ __forceinline__ int origcol(int c) {
    if (c < 3072) { int p = c / 384; return p*1408 + (c - p*384); }
    int q = c - 3072; int p = q >> 10; int w = q & 1023;
    int a = w >> 5, g = (w >> 4) & 1, u = w & 15;
    return p*1408 + 384 + g*512 + a*16 + u;
}

// ---------------- LayerNorm: x f32 (ROWS x DM) -> h bf16 ----------------
__global__ __launch_bounds__(256) void ln_kernel(const float* __restrict__ x,
                                                 const float* __restrict__ sc,
                                                 const float* __restrict__ of,
                                                 __bf16* __restrict__ h) {
    int row = blockIdx.x, t = threadIdx.x;
    const float4 v = *(const float4*)&x[(size_t)row*DM + t*4];
    float s  = v.x + v.y + v.z + v.w;
    float ss = v.x*v.x + v.y*v.y + v.z*v.z + v.w*v.w;
#pragma unroll
    for (int off = 32; off >= 1; off >>= 1) {
        s  += __shfl_xor(s, off);
        ss += __shfl_xor(ss, off);
    }
    __shared__ float rs_[4], rss_[4];
    int wid = t >> 6, lane = t & 63;
    if (lane == 0) { rs_[wid] = s; rss_[wid] = ss; }
    __syncthreads();
    s  = rs_[0] + rs_[1] + rs_[2] + rs_[3];
    ss = rss_[0] + rss_[1] + rss_[2] + rss_[3];
    float mu  = s * (1.f/DM);
    float var = ss * (1.f/DM) - mu*mu;
    float r   = rsqrtf(var + 1e-5f);
    float4 scv = *(const float4*)&sc[t*4];
    float4 ofv = *(const float4*)&of[t*4];
    bf16x4 o;
    o[0] = (__bf16)((v.x-mu)*r*scv.x + ofv.x);
    o[1] = (__bf16)((v.y-mu)*r*scv.y + ofv.y);
    o[2] = (__bf16)((v.z-mu)*r*scv.z + ofv.z);
    o[3] = (__bf16)((v.w-mu)*r*scv.w + ofv.w);
    *(bf16x4*)&h[(size_t)row*DM + t*4] = o;
}

// ------------- transpose+cast: in R x C f32 -> out C x R bf16 (plain) -----------
__global__ __launch_bounds__(256) void transpose_kernel(const float* __restrict__ in,
                                                        __bf16* __restrict__ out,
                                                        int R, int C) {
    __shared__ __bf16 tile[64][72];
    int c0 = blockIdx.x * 64, r0 = blockIdx.y * 64;
    int t = threadIdx.x;
#pragma unroll
    for (int it = 0; it < 4; ++it) {
        int flat = it*1024 + t*4;
        int rl = flat >> 6, cl = flat & 63;
        float4 v = *(const float4*)&in[(size_t)(r0+rl)*C + c0 + cl];
        tile[rl][cl+0] = (__bf16)v.x;
        tile[rl][cl+1] = (__bf16)v.y;
        tile[rl][cl+2] = (__bf16)v.z;
        tile[rl][cl+3] = (__bf16)v.w;
    }
    __syncthreads();
#pragma unroll
    for (int it = 0; it < 4; ++it) {
        int flat = it*1024 + t*4;
        int cl = flat >> 6, rl = flat & 63;
        bf16x4 o;
#pragma unroll
        for (int j = 0; j < 4; ++j) o[j] = tile[rl+j][cl];
        *(bf16x4*)&out[(size_t)(c0+cl)*R + r0 + rl] = o;
    }
}

// ------- transpose+cast with column permutation: w_in (DM x FIN) -> w_in_t [newcol][DM] -------
__global__ __launch_bounds__(256) void transpose_perm_kernel(const float* __restrict__ in,
                                                             __bf16* __restrict__ out) {
    __shared__ __bf16 tile[64][72];
    int c0 = blockIdx.x * 64, r0 = blockIdx.y * 64;
    int t = threadIdx.x;
#pragma unroll
    for (int it = 0; it < 4; ++it) {
        int flat = it*1024 + t*4;
        int rl = flat >> 6, cl = flat & 63;
        int oc = origcol(c0 + cl);             // contiguous over the 4-wide load (16-group aligned)
        float4 v = *(const float4*)&in[(size_t)(r0+rl)*FIN + oc];
        tile[rl][cl+0] = (__bf16)v.x;
        tile[rl][cl+1] = (__bf16)v.y;
        tile[rl][cl+2] = (__bf16)v.z;
        tile[rl][cl+3] = (__bf16)v.w;
    }
    __syncthreads();
#pragma unroll
    for (int it = 0; it < 4; ++it) {
        int flat = it*1024 + t*4;
        int cl = flat >> 6, rl = flat & 63;
        bf16x4 o;
#pragma unroll
        for (int j = 0; j < 4; ++j) o[j] = tile[rl+j][cl];
        *(bf16x4*)&out[(size_t)(c0+cl)*DM + r0 + rl] = o;
    }
}

// ---------------- permuted bias: b_in_perm[c] = b_in[origcol(c)] ----------------
__global__ __launch_bounds__(256) void permbias_kernel(const float* __restrict__ b_in,
                                                       float* __restrict__ bp) {
    int c = blockIdx.x * 256 + threadIdx.x;
    if (c < FIN) bp[c] = b_in[origcol(c)];
}

// ============ 256x256 deep-flight GEMM (round-6 loop) with fused epilogues ============
// GEMM1 (Cf==null): qvk cols -> Cqvk (stride 3072, +bias, bf16); ff cols -> GLU -> Cglu (agb).
// GEMM2 (Cf!=null): f32 partials per z-slice.
#define MFMA4(ACCI, BN) \
    acc[ACCI][BN] = __builtin_amdgcn_mfma_f32_16x16x32_bf16(a[(ACCI)&3][0], b[BN][0], acc[ACCI][BN],0,0,0); \
    acc[ACCI][BN] = __builtin_amdgcn_mfma_f32_16x16x32_bf16(a[(ACCI)&3][1], b[BN][1], acc[ACCI][BN],0,0,0);

__global__ __launch_bounds__(512, 2) void gemm256_kernel(const __bf16* __restrict__ A,
                                                         const __bf16* __restrict__ BT,
                                                         const float* __restrict__ bias,
                                                         __bf16* __restrict__ Cqvk,
                                                         __bf16* __restrict__ Cglu,
                                                         float* __restrict__ Cf,
                                                         int M, int N, int K, int klen) {
    __shared__ __align__(16) char lds[131072];
    int t = threadIdx.x, wid = t >> 6, lane = t & 63;
    int wr = wid >> 2, wc = wid & 3;
    int fr = lane & 15, fq = lane >> 4;
    int kbeg = blockIdx.z * klen;
    int nbx = gridDim.x;
    int bid = blockIdx.y * nbx + blockIdx.x;
    int cpx = (nbx * gridDim.y) >> 3;
    int swz = (bid & 7) * cpx + (bid >> 3);
    int bx = swz % nbx, by = swz / nbx;
    int m0 = by * 256, n0 = bx * 256;

    const __bf16* srcA[4];
    const __bf16* srcB[4];
#pragma unroll
    for (int j = 0; j < 4; ++j) {
        int F = (j*512 + t) * 16;
        int lr = F >> 7, c = (F & 127) ^ ((lr & 7) << 4);
        srcA[j] = A + (size_t)(m0 + lr) * K + kbeg + (c >> 1);
        int row = ((lr >> 5) & 3) * 64 + (lr >> 7) * 32 + (lr & 31);
        srcB[j] = BT + (size_t)(n0 + row) * K + kbeg + (c >> 1);
    }
    int lrAlo[4], lrAhi[4], lrB[4];
#pragma unroll
    for (int i = 0; i < 4; ++i) {
        lrAlo[i] = (wr*128 + i*16 + fr) * 128;
        lrAhi[i] = lrAlo[i] + 64*128;
    }
#pragma unroll
    for (int n = 0; n < 4; ++n)
        lrB[n] = ((n >> 1)*128 + wc*32 + (n & 1)*16 + fr) * 128;
    int swzb = (fr & 7) << 4;
    int cb00 = (fq*16) ^ swzb;
    int cb01 = (64 + fq*16) ^ swzb;

    f32x4 acc[8][4] = {};
    gload16(srcA[0], lds +     0 + wid*1024);
    gload16(srcA[2], lds + 16384 + wid*1024);
    gload16(srcB[0], lds + 32768 + wid*1024);
    gload16(srcB[1], lds + 40960 + wid*1024);
    gload16(srcB[2], lds + 49152 + wid*1024);
    gload16(srcB[3], lds + 57344 + wid*1024);
    gload16(srcA[1], lds +  8192 + wid*1024);
    gload16(srcA[3], lds + 24576 + wid*1024);
    asm volatile("s_waitcnt vmcnt(4)" ::: "memory");
    __builtin_amdgcn_s_barrier();

    int nit = klen >> 6;
    for (int it = 0; it < nit; ++it) {
        const char* bc = lds + (it & 1) * 65536;
        char* bn = lds + ((it & 1) ^ 1) * 65536;
        const char* bcB = bc + 32768;
        int koff = (it + 1) << 6;
        bool pf = (it + 1 < nit);
        bf16x8 a[4][2], b[4][2];
        // P0
#pragma unroll
        for (int i = 0; i < 4; ++i) {
            a[i][0] = *(const bf16x8*)(bc + lrAlo[i] + cb00);
            a[i][1] = *(const bf16x8*)(bc + lrAlo[i] + cb01);
        }
        b[0][0] = *(const bf16x8*)(bcB + lrB[0] + cb00);
        b[0][1] = *(const bf16x8*)(bcB + lrB[0] + cb01);
        b[1][0] = *(const bf16x8*)(bcB + lrB[1] + cb00);
        b[1][1] = *(const bf16x8*)(bcB + lrB[1] + cb01);
        if (pf) {
            gload16(srcA[0] + koff, bn +     0 + wid*1024);
            gload16(srcA[2] + koff, bn + 16384 + wid*1024);
            gload16(srcB[0] + koff, bn + 32768 + wid*1024);
            gload16(srcB[1] + koff, bn + 40960 + wid*1024);
            gload16(srcB[2] + koff, bn + 49152 + wid*1024);
            gload16(srcB[3] + koff, bn + 57344 + wid*1024);
            gload16(srcA[1] + koff, bn +  8192 + wid*1024);
            gload16(srcA[3] + koff, bn + 24576 + wid*1024);
        }
        __builtin_amdgcn_s_setprio(1);
#pragma unroll
        for (int i = 0; i < 4; ++i) { MFMA4(i,0) MFMA4(i,1) }
        __builtin_amdgcn_s_setprio(0);
        if (pf) asm volatile("s_waitcnt vmcnt(10)" ::: "memory");
        else    asm volatile("s_waitcnt vmcnt(2)" ::: "memory");
        __builtin_amdgcn_s_barrier();
        // P1
        b[2][0] = *(const bf16x8*)(bcB + lrB[2] + cb00);
        b[2][1] = *(const bf16x8*)(bcB + lrB[2] + cb01);
        b[3][0] = *(const bf16x8*)(bcB + lrB[3] + cb00);
        b[3][1] = *(const bf16x8*)(bcB + lrB[3] + cb01);
        __builtin_amdgcn_s_setprio(1);
#pragma unroll
        for (int i = 0; i < 4; ++i) { MFMA4(i,2) MFMA4(i,3) }
        __builtin_amdgcn_s_setprio(0);
        if (pf) asm volatile("s_waitcnt vmcnt(8)" ::: "memory");
        else    asm volatile("s_waitcnt vmcnt(0)" ::: "memory");
        __builtin_amdgcn_s_barrier();
        // P2
#pragma unroll
        for (int i = 0; i < 4; ++i) {
            a[i][0] = *(const bf16x8*)(bc + lrAhi[i] + cb00);
            a[i][1] = *(const bf16x8*)(bc + lrAhi[i] + cb01);
        }
        __builtin_amdgcn_s_setprio(1);
#pragma unroll
        for (int i = 0; i < 4; ++i) { MFMA4(4+i,0) MFMA4(4+i,1) MFMA4(4+i,2) MFMA4(4+i,3) }
        __builtin_amdgcn_s_setprio(0);
        if (pf) {
            asm volatile("s_waitcnt vmcnt(4)" ::: "memory");
            __builtin_amdgcn_s_barrier();
        }
    }
    // ---------------- epilogues ----------------
    if (Cf) {
        float* Cz = Cf + (size_t)blockIdx.z * M * N;
#pragma unroll
        for (int i = 0; i < 8; ++i)
#pragma unroll
            for (int n = 0; n < 4; ++n) {
                int col = n0 + wc*64 + (n >> 1)*32 + (n & 1)*16 + fr;
#pragma unroll
                for (int r = 0; r < 4; ++r) {
                    int row = m0 + wr*128 + i*16 + fq*4 + r;
                    Cz[(size_t)row*N + col] = acc[i][n][r];
                }
            }
    } else if (n0 < 3072) {
        // qvk region: bias + bf16 -> Cqvk (stride 3072)
#pragma unroll
        for (int i = 0; i < 8; ++i)
#pragma unroll
            for (int n = 0; n < 4; ++n) {
                int col = n0 + wc*64 + (n >> 1)*32 + (n & 1)*16 + fr;
                float bv = bias[col];
#pragma unroll
                for (int r = 0; r < 4; ++r) {
                    int row = m0 + wr*128 + i*16 + fq*4 + r;
                    Cqvk[(size_t)row*3072 + col] = (__bf16)(acc[i][n][r] + bv);
                }
            }
    } else {
        // ff region: GLU on (out,gate) fragment pairs -> Cglu (agb, stride DOUT)
        int q = n0 - 3072;
        int p = q >> 10;
#pragma unroll
        for (int m = 0; m < 2; ++m) {
            int off = wc*64 + m*32;
            float bo = bias[n0 + off + fr];
            float bg = bias[n0 + off + 16 + fr];
            int j = (((q & 1023) + off) >> 5) * 16 + fr;
            int colg = p*640 + 128 + j;
#pragma unroll
            for (int i = 0; i < 8; ++i)
#pragma unroll
                for (int r = 0; r < 4; ++r) {
                    int row = m0 + wr*128 + i*16 + fq*4 + r;
                    float ov = acc[i][2*m][r] + bo;
                    float gv = acc[i][2*m+1][r] + bg;
                    float e2 = __expf(1.5957691216057308f*(gv + 0.044715f*gv*gv*gv));
                    float gl = gv * (1.f - 1.f/(e2 + 1.f));
                    Cglu[(size_t)row*DOUT + colg] = (__bf16)(ov * gl);
                }
        }
    }
}

// ---------------- out = p0+p1+p2+p3 + bias (f32, vectorized) ----------------
__global__ __launch_bounds__(256) void addbias_kernel(const float* __restrict__ pk,
                                                      const float* __restrict__ bias,
                                                      float* __restrict__ out) {
    int idx = blockIdx.x * 256 + threadIdx.x;
    const size_t stride = (size_t)ROWS * DM / 4;
    float4 a0 = ((const float4*)pk)[idx];
    float4 a1 = ((const float4*)pk)[idx + stride];
    float4 a2 = ((const float4*)pk)[idx + 2*stride];
    float4 a3 = ((const float4*)pk)[idx + 3*stride];
    float4 bb = ((const float4*)bias)[idx & 255];
    float4 o;
    o.x = a0.x + a1.x + a2.x + a3.x + bb.x;
    o.y = a0.y + a1.y + a2.y + a3.y + bb.y;
    o.z = a0.z + a1.z + a2.z + a3.z + bb.z;
    o.w = a0.w + a1.w + a2.w + a3.w + bb.w;
    ((float4*)out)[idx] = o;
}

// ==== fused rope + split + V-transpose: proj2 [ROWS][3072] -> qh, kh (b,h,s,d), vt (b,h,d,s) ====
__global__ __launch_bounds__(256) void rqkv_kernel(const __bf16* __restrict__ proj2,
                                                   __bf16* __restrict__ qh,
                                                   __bf16* __restrict__ kh,
                                                   __bf16* __restrict__ vt) {
    __shared__ __bf16 tile[64*144];
    int r0 = blockIdx.x * 64;
    int p  = blockIdx.y;
    int t  = threadIdx.x;
    int b  = r0 >> 11;
    int bh = b*NSH + p;
#pragma unroll
    for (int j = 0; j < 4; ++j) {
        int e = (j*256 + t) * 8;
        int sl = e >> 7, d = e & 127;
        const __bf16* rowp = proj2 + (size_t)(r0 + sl)*3072 + p*384;
        bf16x8 vq = *(const bf16x8*)&rowp[d];
        bf16x8 vv = *(const bf16x8*)&rowp[128 + d];
        bf16x8 vk = *(const bf16x8*)&rowp[256 + d];
        int s = (r0 + sl) & (S_ - 1);
        if (d < 64) {
#pragma unroll
            for (int u = 0; u < 4; ++u) {
                int i = (d >> 1) + u;
                float inv = exp2f(-(float)i * 0.4152410118609203f);
                float ang = (float)s * inv;
                float cn = __cosf(ang), sn = __sinf(ang);
                float q0 = vq[2*u], q1 = vq[2*u+1];
                float k0 = vk[2*u], k1 = vk[2*u+1];
                vq[2*u]   = (__bf16)(q0*cn - q1*sn);
                vq[2*u+1] = (__bf16)(q1*cn + q0*sn);
                vk[2*u]   = (__bf16)(k0*cn - k1*sn);
                vk[2*u+1] = (__bf16)(k1*cn + k0*sn);
            }
        }
#pragma unroll
        for (int u = 0; u < 8; ++u) vq[u] = (__bf16)((float)vq[u] * 0.125f);
        size_t o = ((size_t)bh * S_ + s) * DH + d;
        *(bf16x8*)&qh[o] = vq;
        *(bf16x8*)&kh[o] = vk;
        int ch = ((d >> 3) + sl) & 15;
        *(bf16x8*)&tile[sl*144 + ch*8] = vv;
    }
    __syncthreads();
#pragma unroll
    for (int j = 0; j < 4; ++j) {
        int e = (j*256 + t) * 8;
        int d = e >> 6, sb = e & 63;
        bf16x8 o;
#pragma unroll
        for (int u = 0; u < 8; ++u) {
            int sl = sb + u;
            int ch = ((d >> 3) + sl) & 15;
            o[u] = tile[sl*144 + ch*8 + (d & 7)];
        }
        size_t ov = ((size_t)bh * DH + d) * S_ + (r0 & (S_ - 1)) + sb;
        *(bf16x8*)&vt[ov] = o;
    }
}

// ---------------------- flash attention, causal + bias ----------------------
__device__ __forceinline__ void stage_kv(const __bf16* Kb, const __bf16* Vg,
                                         char* KsB, char* VsB,
                                         int kvbase, int t, int wid) {
#pragma unroll
    for (int j = 0; j < 4; ++j) {
        int F = (j*256 + t)*16;
        int r = F >> 8, c = F & 255;
        gload16(Kb + (size_t)(kvbase + r)*DH + ((c ^ ((r & 7) << 4)) >> 1),
                KsB + j*4096 + (wid << 10));
    }
#pragma unroll
    for (int j = 0; j < 4; ++j) {
        int F = (j*256 + t)*16;
        int r = F >> 7, c = F & 127;
        gload16(Vg + (size_t)r*S_ + kvbase + ((c ^ ((r & 7) << 4)) >> 1),
                VsB + j*4096 + (wid << 10));
    }
}

__global__ __launch_bounds__(256, 2) void attn_kernel(const __bf16* __restrict__ qh,
                                                      const __bf16* __restrict__ kh,
                                                      const __bf16* __restrict__ vt,
                                                      const float* __restrict__ ab,
                                                      __bf16* __restrict__ ag) {
    __shared__ __bf16 Ks[2*8192];
    __shared__ __bf16 Vs[2*8192];
    __shared__ __bf16 Ps[4][16*72];
    int bh = blockIdx.y;
    int b = bh >> 3, hh = bh & 7;
    int xr = blockIdx.x;
    int qb = (xr & 1) ? (31 - (xr >> 1)) : (xr >> 1);
    int q0 = qb * 64;
    int t = threadIdx.x, wid = t >> 6, lane = t & 63;
    int fr = lane & 15, fkb = (lane >> 4) * 16;
    const __bf16* Qb = qh + (size_t)bh * S_ * DH;
    const __bf16* Kb = kh + (size_t)bh * S_ * DH;
    const __bf16* Vg = vt + (size_t)bh * DH * S_;
    bf16x8 qf[4];
#pragma unroll
    for (int kk = 0; kk < 4; ++kk)
        qf[kk] = *(const bf16x8*)&Qb[(size_t)(q0 + wid*16 + fr)*DH + kk*32 + (lane>>4)*8];
    float m[4] = {-3e38f, -3e38f, -3e38f, -3e38f};
    float l[4] = {0.f, 0.f, 0.f, 0.f};
    f32x4 o[8] = {};
    int rowb = q0 + wid*16 + (lane >> 4)*4;
    int nit = qb + 1;
    stage_kv(Kb, Vg, (char*)Ks, (char*)Vs, 0, t, wid);
    for (int it = 0; it < nit; ++it) {
        int kv0 = it * 64, cur = it & 1;
        float abv[4][4];
#pragma unroll
        for (int n = 0; n < 4; ++n)
#pragma unroll
            for (int r = 0; r < 4; ++r)
                abv[n][r] = ab[(size_t)(rowb + r)*S_ + kv0 + n*16 + fr];
        if (it + 1 < nit) {
            stage_kv(Kb, Vg, (char*)Ks + (cur^1)*16384, (char*)Vs + (cur^1)*16384,
                     kv0 + 64, t, wid);
            asm volatile("s_waitcnt vmcnt(8)" ::: "memory");
        } else {
            asm volatile("s_waitcnt vmcnt(0)" ::: "memory");
        }
        __builtin_amdgcn_s_barrier();
        const char* KsC = (const char*)Ks + cur*16384;
        float pv[4][4];
        __builtin_amdgcn_s_setprio(1);
#pragma unroll
        for (int n = 0; n < 4; ++n) {
            f32x4 sacc = {};
#pragma unroll
            for (int kk = 0; kk < 4; ++kk) {
                int row = n*16 + fr;
                int c2 = (kk*64 + fkb) ^ ((fr & 7) << 4);
                bf16x8 kf = *(const bf16x8*)(KsC + row*256 + c2);
                sacc = __builtin_amdgcn_mfma_f32_16x16x32_bf16(qf[kk], kf, sacc, 0, 0, 0);
            }
#pragma unroll
            for (int r = 0; r < 4; ++r) pv[n][r] = sacc[r];
        }
        __builtin_amdgcn_s_setprio(0);
#pragma unroll
        for (int n = 0; n < 4; ++n) {
            int col = kv0 + n*16 + fr;
#pragma unroll
            for (int r = 0; r < 4; ++r)
                pv[n][r] += abv[n][r] + (col <= rowb + r ? 0.f : -1e10f);
        }
        float alpha[4];
#pragma unroll
        for (int r = 0; r < 4; ++r) {
            float mx = fmaxf(fmaxf(pv[0][r], pv[1][r]), fmaxf(pv[2][r], pv[3][r]));
#pragma unroll
            for (int off = 8; off >= 1; off >>= 1) mx = fmaxf(mx, __shfl_xor(mx, off));
            float mn = fmaxf(m[r], mx);
            alpha[r] = __expf(m[r] - mn);
            m[r] = mn;
            float sum = 0.f;
#pragma unroll
            for (int n = 0; n < 4; ++n) { pv[n][r] = __expf(pv[n][r] - mn); sum += pv[n][r]; }
#pragma unroll
            for (int off = 8; off >= 1; off >>= 1) sum += __shfl_xor(sum, off);
            l[r] = l[r]*alpha[r] + sum;
        }
#pragma unroll
        for (int nf = 0; nf < 8; ++nf)
#pragma unroll
            for (int r = 0; r < 4; ++r) o[nf][r] *= alpha[r];
#pragma unroll
        for (int n = 0; n < 4; ++n)
#pragma unroll
            for (int r = 0; r < 4; ++r)
                Ps[wid][((lane >> 4)*4 + r)*72 + n*16 + fr] = (__bf16)pv[n][r];
        asm volatile("s_waitcnt lgkmcnt(0)" ::: "memory");
        __builtin_amdgcn_sched_barrier(0);
        bf16x8 pf[2];
#pragma unroll
        for (int kk = 0; kk < 2; ++kk)
            pf[kk] = *(const bf16x8*)&Ps[wid][fr*72 + kk*32 + (lane>>4)*8];
        const char* VsC = (const char*)Vs + cur*16384;
        __builtin_amdgcn_s_setprio(1);
#pragma unroll
        for (int nf = 0; nf < 8; ++nf) {
#pragma unroll
            for (int kk = 0; kk < 2; ++kk) {
                int row = nf*16 + fr;
                int c2 = (kk*64 + fkb) ^ ((fr & 7) << 4);
                bf16x8 vf = *(const bf16x8*)(VsC + row*128 + c2);
                o[nf] = __builtin_amdgcn_mfma_f32_16x16x32_bf16(pf[kk], vf, o[nf], 0, 0, 0);
            }
        }
        __builtin_amdgcn_s_setprio(0);
        asm volatile("s_waitcnt lgkmcnt(0)" ::: "memory");
        __builtin_amdgcn_sched_barrier(0);
        __builtin_amdgcn_s_barrier();
    }
    int rq = (lane >> 4) * 4;
#pragma unroll
    for (int r = 0; r < 4; ++r) {
        float inv = 1.f / l[r];
#pragma unroll
        for (int nf = 0; nf < 8; ++nf) {
            int qr = q0 + wid*16 + rq + r;
            int d = nf*16 + fr;
            ag[((size_t)(b*S_ + qr))*DOUT + hh*640 + d] = (__bf16)(o[nf][r] * inv);
        }
    }
}

extern "C" void kernel_launch(void* const* d_in, const int* in_sizes, int n_in,
                              void* d_out, int out_size, void* d_ws, size_t ws_size,
                              hipStream_t stream) {
    const float* x     = (const float*)d_in[0];
    const float* ab    = (const float*)d_in[1];
    const float* lns   = (const float*)d_in[2];
    const float* lno   = (const float*)d_in[3];
    const float* w_in  = (const float*)d_in[4];
    const float* b_in  = (const float*)d_in[5];
    const float* w_out = (const float*)d_in[6];
    const float* b_out = (const float*)d_in[7];
    float* out = (float*)d_out;
    char* ws = (char*)d_ws;

    __bf16* w_in_t  = (__bf16*)(ws);                 //         0: 11264x1024 bf16 (23,068,672)
    __bf16* w_out_t = (__bf16*)(ws +  23068672);     //  23068672: 1024x5120 bf16 (10,485,760)
    __bf16* hbuf    = (__bf16*)(ws +  33554432);     //  33554432: 4096x1024 bf16 (8,388,608)
    __bf16* proj2   = (__bf16*)(ws +  41943040);     //  41943040: 4096x3072 bf16 (25,165,824)
    __bf16* vtb     = (__bf16*)(ws +  67108864);     //  67108864: 16x128x2048 bf16 (8,388,608)
    __bf16* qh      = (__bf16*)(ws +  75497472);     //  75497472: (8,388,608)
    __bf16* kh      = (__bf16*)(ws +  83886080);     //  83886080: (8,388,608)
    __bf16* agb     = (__bf16*)(ws +  92274688);     //  92274688: 4096x5120 bf16 (41,943,040)
    float*  pk      = (float*)(ws + 134217728);      // 134217728: 4 x 4096x1024 f32 (67,108,864)
    float*  bperm   = (float*)(ws + 134217728);      // reuses pk region (GEMM1 phase only)

    transpose_perm_kernel<<<dim3(FIN/64, DM/64), 256, 0, stream>>>(w_in, w_in_t);
    transpose_kernel<<<dim3(DM/64, DOUT/64), 256, 0, stream>>>(w_out, w_out_t, DOUT, DM);
    permbias_kernel<<<(FIN + 255)/256, 256, 0, stream>>>(b_in, bperm);
    ln_kernel<<<ROWS, 256, 0, stream>>>(x, lns, lno, hbuf);
    gemm256_kernel<<<dim3(FIN/256, ROWS/256, 1), 512, 0, stream>>>(hbuf, w_in_t, bperm,
                                                                   proj2, agb, nullptr,
                                                                   ROWS, FIN, DM, DM);
    rqkv_kernel<<<dim3(ROWS/64, NSH), 256, 0, stream>>>(proj2, qh, kh, vtb);
    attn_kernel<<<dim3(S_/64, B_*NSH), 256, 0, stream>>>(qh, kh, vtb, ab, agb);
    gemm256_kernel<<<dim3(DM/256, ROWS/256, 4), 512, 0, stream>>>(agb, w_out_t, nullptr,
                                                                  nullptr, nullptr, pk,
                                                                  ROWS, DM, DOUT, DOUT/4);
    addbias_kernel<<<ROWS*DM/1024, 256, 0, stream>>>(pk, b_out, out);
}